// Round 12
// baseline (240.633 us; speedup 1.0000x reference)
//
#include <hip/hip_runtime.h>
#include <math.h>

#define Bsz 2
#define Ssz 1024
#define Dsz 1024
#define Hn 16
#define DHsz 64
#define QKV3 3072
#define SCALE 0.125f

typedef __bf16 bf16;
typedef bf16 bf16x8 __attribute__((ext_vector_type(8)));
typedef bf16 bf16x4 __attribute__((ext_vector_type(4)));
typedef float f32x4 __attribute__((ext_vector_type(4)));

#define MFMA(a, b, c) __builtin_amdgcn_mfma_f32_16x16x32_bf16(a, b, c, 0, 0, 0)
#define LDT 72

// ---------------------------------------------------------------------------
// cast3: all three fp32->bf16 casts in one launch (segmented by block id)
// x: 2M elems (blocks 0..2047), qkv_w: 3M (2048..5119), out_w: 1M (5120..6143)
// ---------------------------------------------------------------------------
__global__ void cast3(const float* __restrict__ x, const float* __restrict__ qw,
                      const float* __restrict__ ow, bf16* __restrict__ xh,
                      bf16* __restrict__ wh, bf16* __restrict__ owh) {
  int bid = blockIdx.x;
  const float* src;
  bf16* dst;
  int base;
  if (bid < 2048) { src = x;  dst = xh;  base = bid * 1024; }
  else if (bid < 5120) { src = qw; dst = wh;  base = (bid - 2048) * 1024; }
  else { src = ow; dst = owh; base = (bid - 5120) * 1024; }
  int idx = base + threadIdx.x * 4;
  float4 v = *(const float4*)(src + idx);
  bf16x4 hv = {(bf16)v.x, (bf16)v.y, (bf16)v.z, (bf16)v.w};
  *(bf16x4*)(dst + idx) = hv;
}

// ---------------------------------------------------------------------------
// tkw: tk table (kerple inlined) + dape weight fragments, one launch.
// tk[o][n] = { b1[n] + sum_h w1[n][16+h]*kb(|o-1024|,h),  kb(|o-1024|,n) }
// block 128: wfrag -> wf[0..511]=w1d (hi|lo), wf[512..1023]=w2a
// ---------------------------------------------------------------------------
__global__ void tkw(const float* __restrict__ bias_p, const float* __restrict__ bias_a,
                    const float* __restrict__ w1, const float* __restrict__ b1,
                    const float* __restrict__ w2, float2* __restrict__ tk,
                    bf16* __restrict__ wf) {
  if (blockIdx.x == 128) {
    int lane = threadIdx.x;
    if (lane < 64) {
      int l15 = lane & 15, q8 = (lane >> 4) << 3;
      bf16x8 w1d, w2a;
#pragma unroll
      for (int e = 0; e < 8; ++e) {
        int k = q8 + e;
        if (k < 16) {
          w1d[e] = (bf16)w1[l15 * 32 + k];
        } else {
          float w = w1[l15 * 32 + k - 16];
          w1d[e] = (bf16)(w - (float)(bf16)w);
        }
        w2a[e] = (bf16)w2[l15 * 16 + (k & 15)];
      }
      *(bf16x8*)(wf + lane * 8) = w1d;
      *(bf16x8*)(wf + 512 + lane * 8) = w2a;
    }
    return;
  }
  int idx = blockIdx.x * 256 + threadIdx.x;  // 32768
  int o = idx >> 4, n = idx & 15;
  int d = o - 1024; if (d < 0) d = -d; if (d > 1023) d = 1023;
  float dd = (float)d;
  float t1 = b1[n], kbn = 0.f;
#pragma unroll
  for (int h = 0; h < 16; ++h) {
    float p = fmaxf(bias_p[h], 0.01f), a = fmaxf(bias_a[h], 0.01f);
    float kb = -p * log1pf(a * dd);
    t1 += w1[n * 32 + 16 + h] * kb;
    if (h == n) kbn = kb;
  }
  tk[idx] = make_float2(t1, kbn);
}

// ---------------------------------------------------------------------------
// K1: qkv_bf = bf16( x_h @ w_h^T )  1-term MFMA, tile 128x96 -> 512 blocks
// (LDS-staged; unchanged from r11)
// ---------------------------------------------------------------------------
__global__ __launch_bounds__(256, 3) void k1_qkv(const bf16* __restrict__ A,
                                                 const bf16* __restrict__ B,
                                                 bf16* __restrict__ C) {
  __shared__ __align__(16) bf16 sA[128 * LDT];
  __shared__ __align__(16) bf16 sB[96 * LDT];
  const int tid = threadIdx.x;
  const int lane = tid & 63, wv = tid >> 6;
  const int wr = wv >> 1, wc = wv & 1;
  const int l15 = lane & 15, q8 = (lane >> 4) << 3, q4 = (lane >> 4) << 2;
  const int m0 = blockIdx.y * 128, n0 = blockIdx.x * 96;
  const int r0 = tid >> 3, c8 = (tid & 7) << 3;

  f32x4 acc[4][3];
#pragma unroll
  for (int t = 0; t < 4; ++t)
#pragma unroll
    for (int u = 0; u < 3; ++u)
#pragma unroll
      for (int r = 0; r < 4; ++r) acc[t][u][r] = 0.f;

  bf16x8 rA[4], rB[3];
#define K1_LOAD(kt)                                                         \
  {                                                                         \
    _Pragma("unroll") for (int c = 0; c < 4; ++c)                           \
      rA[c] = *(const bf16x8*)(A + (size_t)(m0 + c * 32 + r0) * Dsz + (kt) + c8);  \
    _Pragma("unroll") for (int c = 0; c < 3; ++c)                           \
      rB[c] = *(const bf16x8*)(B + (size_t)(n0 + c * 32 + r0) * Dsz + (kt) + c8);  \
  }

  K1_LOAD(0)
  for (int kt = 0; kt < Dsz; kt += 64) {
    __syncthreads();
#pragma unroll
    for (int c = 0; c < 4; ++c) *(bf16x8*)&sA[(c * 32 + r0) * LDT + c8] = rA[c];
#pragma unroll
    for (int c = 0; c < 3; ++c) *(bf16x8*)&sB[(c * 32 + r0) * LDT + c8] = rB[c];
    __syncthreads();
    if (kt + 64 < Dsz) K1_LOAD(kt + 64)
#pragma unroll
    for (int ks = 0; ks < 64; ks += 32) {
      bf16x8 fa[4], fb[3];
#pragma unroll
      for (int t = 0; t < 4; ++t)
        fa[t] = *(const bf16x8*)&sA[(wr * 64 + t * 16 + l15) * LDT + ks + q8];
#pragma unroll
      for (int u = 0; u < 3; ++u)
        fb[u] = *(const bf16x8*)&sB[(wc * 48 + u * 16 + l15) * LDT + ks + q8];
#pragma unroll
      for (int t = 0; t < 4; ++t)
#pragma unroll
        for (int u = 0; u < 3; ++u) acc[t][u] = MFMA(fa[t], fb[u], acc[t][u]);
    }
  }
#pragma unroll
  for (int t = 0; t < 4; ++t)
#pragma unroll
    for (int u = 0; u < 3; ++u) {
      int col = n0 + wc * 48 + u * 16 + l15;
#pragma unroll
      for (int r = 0; r < 4; ++r) {
        int row = m0 + wr * 64 + t * 16 + q4 + r;
        C[(size_t)row * QKV3 + col] = (bf16)acc[t][u][r];
      }
    }
#undef K1_LOAD
}

// ---------------------------------------------------------------------------
// pack V transposed: v_t[b][h][d][j]
// ---------------------------------------------------------------------------
__global__ void pack_vt(const bf16* __restrict__ qkv, bf16* __restrict__ vt) {
  __shared__ __align__(16) bf16 T[64 * LDT];
  const int tid = threadIdx.x;
  const int bh = blockIdx.y, b = bh >> 4, h = bh & 15;
  const int j0 = blockIdx.x * 64;
#pragma unroll
  for (int c = 0; c < 2; ++c) {
    int lin = c * 256 + tid;
    int jr = lin >> 3, d8 = (lin & 7) << 3;
    bf16x8 v = *(const bf16x8*)(qkv + (size_t)(b * Ssz + j0 + jr) * QKV3 + 2048 + h * DHsz + d8);
#pragma unroll
    for (int e = 0; e < 8; ++e) T[(d8 + e) * LDT + jr] = v[e];
  }
  __syncthreads();
#pragma unroll
  for (int c = 0; c < 2; ++c) {
    int lin = c * 256 + tid;
    int d = lin >> 3, j8 = (lin & 7) << 3;
    bf16x8 o = *(const bf16x8*)&T[d * LDT + j8];
    *(bf16x8*)(vt + ((size_t)(b * Hn + h) * DHsz + d) * Ssz + j0 + j8) = o;
  }
}

// ---------------------------------------------------------------------------
// K2: scores = bf16(SCALE * Q @ K^T). LDS-FREE: K=64 -> each element belongs to
// exactly one lane's frag; direct global frag loads (16 rows x 64B, line-complete).
// ---------------------------------------------------------------------------
__global__ __launch_bounds__(256, 3) void k2_qk(const bf16* __restrict__ qkv,
                                                bf16* __restrict__ scores) {
  const int tid = threadIdx.x;
  const int lane = tid & 63, wv = tid >> 6;
  const int wr = wv >> 1, wc = wv & 1;
  const int l15 = lane & 15, q8 = (lane >> 4) << 3, q4 = (lane >> 4) << 2;
  const int z = blockIdx.z, b = z >> 4, h = z & 15;
  const int i0 = blockIdx.y * 128, j0 = blockIdx.x * 128;
  const bf16* Ab = qkv + (size_t)(b * Ssz + i0 + wr * 64 + l15) * QKV3 + h * DHsz + q8;
  const bf16* Bb = qkv + (size_t)(b * Ssz + j0 + wc * 64 + l15) * QKV3 + Ssz + h * DHsz + q8;

  bf16x8 fa[2][4], fb[2][4];
#pragma unroll
  for (int s = 0; s < 2; ++s)
#pragma unroll
    for (int t = 0; t < 4; ++t) {
      fa[s][t] = *(const bf16x8*)(Ab + (size_t)(t * 16) * QKV3 + s * 32);
      fb[s][t] = *(const bf16x8*)(Bb + (size_t)(t * 16) * QKV3 + s * 32);
    }
  f32x4 acc[4][4];
#pragma unroll
  for (int t = 0; t < 4; ++t)
#pragma unroll
    for (int u = 0; u < 4; ++u)
#pragma unroll
      for (int r = 0; r < 4; ++r) acc[t][u][r] = 0.f;
#pragma unroll
  for (int s = 0; s < 2; ++s)
#pragma unroll
    for (int t = 0; t < 4; ++t)
#pragma unroll
      for (int u = 0; u < 4; ++u) acc[t][u] = MFMA(fa[s][t], fb[s][u], acc[t][u]);

  bf16* dstp = scores + ((size_t)(b * Hn + h) << 20);
#pragma unroll
  for (int t = 0; t < 4; ++t)
#pragma unroll
    for (int u = 0; u < 4; ++u) {
      int col = j0 + wc * 64 + u * 16 + l15;
#pragma unroll
      for (int r = 0; r < 4; ++r) {
        int row = i0 + wr * 64 + t * 16 + q4 + r;
        dstp[((size_t)row << 10) + col] = (bf16)(acc[t][u][r] * SCALE);
      }
    }
}

// ---------------------------------------------------------------------------
// K3: DAPE MLP v4 — lgt + contiguous-write exp phase + tk table. (unchanged)
// ---------------------------------------------------------------------------
__device__ __forceinline__ float gelu_fast(float x) {
  float z = fabsf(x) * 0.70710678118654752f;
  float t = __builtin_amdgcn_rcpf(fmaf(0.3275911f, z, 1.0f));
  float poly = t * fmaf(t, fmaf(t, fmaf(t, fmaf(t, 1.061405429f, -1.453152027f),
                                        1.421413741f), -0.284496736f), 0.254829592f);
  float erfa = 1.0f - poly * __expf(-z * z);
  float erfs = copysignf(erfa, x);
  return 0.5f * x * (1.0f + erfs);
}

#define SHS 264  // sH row stride (bf16)
#define LGS 264  // lgt row stride (fp32)

__global__ __launch_bounds__(256, 5) void dape_softmax(bf16* scores,
                                                       const float2* __restrict__ tk,
                                                       const bf16* __restrict__ wf,
                                                       const float* __restrict__ b2,
                                                       float* __restrict__ sums) {
  const int c = blockIdx.x;   // chunk 0..3 (256 j each)
  const int i = blockIdx.y;   // query row
  const int b = blockIdx.z;   // batch
  const int tid = threadIdx.x;
  const int lane = tid & 63, wv = tid >> 6;
  const int l15 = lane & 15, q = lane >> 4;
  const int q8 = q << 3, q4 = q << 2;

  __shared__ bf16 sH[Hn][SHS];                   // 8448 B raw bf16 scores
  __shared__ float lgt[Hn][LGS];                 // 16896 B logits
  __shared__ __align__(16) bf16 hdnS[4][16][40]; // 5120 B (cols 16..31 zeroed)

  const bf16x8 w1d = *(const bf16x8*)(wf + lane * 8);
  const bf16x8 w2a = *(const bf16x8*)(wf + 512 + lane * 8);
  const float bias2 = b2[l15];

  if (lane < 32) {
    int row = lane >> 1, col = 16 + (lane & 1) * 8;
    *(bf16x8*)&hdnS[wv][row][col] = (bf16x8){};
  }

  // ---- stage this wave's 64-j slice of all 16 head rows (bf16x8 copies) ----
  const int jw = wv * 64;
  const bf16* srow = scores + ((size_t)(b * Hn) << 20) + ((size_t)i << 10) + c * 256;
#pragma unroll
  for (int t = 0; t < 2; ++t) {
    int h = t * 8 + (lane >> 3);
    int col = jw + (lane & 7) * 8;
    *(bf16x8*)&sH[h][col] = *(const bf16x8*)(srow + ((size_t)h << 20) + col);
  }
  // no barrier: each wave touches only its own j-columns until the exp phase

  const float2* tkp = tk + ((size_t)(c * 256 + jw + q4 - i + 1024) << 4) + l15;

  for (int jt = 0; jt < 4; ++jt) {
    const int j0c = jw + jt * 16;
    bf16x8 a1;
#pragma unroll
    for (int e = 0; e < 8; ++e) a1[e] = sH[(q8 + e) & 15][j0c + l15];
    float2 tkv[4];
#pragma unroll
    for (int r = 0; r < 4; ++r) tkv[r] = tkp[r * 16];
    f32x4 c1 = {tkv[0].x, tkv[1].x, tkv[2].x, tkv[3].x};
    c1 = MFMA(a1, w1d, c1);
#pragma unroll
    for (int r = 0; r < 4; ++r) hdnS[wv][q4 + r][l15] = (bf16)gelu_fast(c1[r]);
    bf16x8 a2 = *(const bf16x8*)&hdnS[wv][l15][q8];
    f32x4 c2 = {bias2, bias2, bias2, bias2};
    c2 = MFMA(a2, w2a, c2);
    bf16x4 sc4 = *(const bf16x4*)&sH[l15][j0c + q4];
    f32x4 lg;
#pragma unroll
    for (int r = 0; r < 4; ++r) lg[r] = (float)sc4[r] + tkv[r].y + c2[r];
    *(f32x4*)&lgt[l15][j0c + q4] = lg;
    tkp += 256;  // +16 o
  }
  __syncthreads();

  // ---- exp (no max-sub; logits bounded) + partial sums, contiguous writes ----
#pragma unroll
  for (int hh = 0; hh < 4; ++hh) {
    const int h = wv * 4 + hh;
    f32x4 v0 = *(const f32x4*)&lgt[h][lane * 4];
    float s = 0.f;
#pragma unroll
    for (int e = 0; e < 4; ++e) { v0[e] = __expf(v0[e]); s += v0[e]; }
#pragma unroll
    for (int off = 32; off > 0; off >>= 1) s += __shfl_xor(s, off, 64);
    bf16* dst = scores + ((size_t)(b * Hn + h) << 20) + ((size_t)i << 10) + c * 256;
    bf16x4 p0 = {(bf16)v0[0], (bf16)v0[1], (bf16)v0[2], (bf16)v0[3]};
    *(bf16x4*)(dst + lane * 4) = p0;
    if (lane == 0) sums[((((b << 10) + i) << 4) + h) * 4 + c] = s;
  }
}

// ---------------------------------------------------------------------------
// K4: aout = (P_un @ V) / sum(chunks). LDS-FREE: direct global frag loads,
// register double-buffer over K (64-wide steps).
// ---------------------------------------------------------------------------
__global__ __launch_bounds__(256, 4) void k4_av(const bf16* __restrict__ attn,
                                                const bf16* __restrict__ vt,
                                                const float* __restrict__ sums,
                                                bf16* __restrict__ aout) {
  const int tid = threadIdx.x;
  const int lane = tid & 63, wv = tid >> 6;
  const int wr = wv >> 1, wc = wv & 1;
  const int l15 = lane & 15, q8 = (lane >> 4) << 3, q4 = (lane >> 4) << 2;
  const int i0 = blockIdx.x * 64, h = blockIdx.y, b = blockIdx.z;
  const bf16* a0p = attn + ((size_t)(b * Hn + h) << 20) + ((size_t)(i0 + wr * 32 + l15) << 10) + q8;
  const bf16* a1p = a0p + (16 << 10);
  const bf16* b0p = vt + (size_t)(b * Hn + h) * DHsz * Ssz + ((size_t)(wc * 32 + l15) << 10) + q8;
  const bf16* b1p = b0p + (16 << 10);

  f32x4 acc[2][2];
#pragma unroll
  for (int t = 0; t < 2; ++t)
#pragma unroll
    for (int u = 0; u < 2; ++u)
#pragma unroll
      for (int r = 0; r < 4; ++r) acc[t][u][r] = 0.f;

  bf16x8 ca[2][2], cb[2][2], na[2][2], nb[2][2];
#define K4_LD(A_, B_, kt)                                 \
  {                                                       \
    _Pragma("unroll") for (int s = 0; s < 2; ++s) {       \
      A_[s][0] = *(const bf16x8*)(a0p + (kt) + s * 32);   \
      A_[s][1] = *(const bf16x8*)(a1p + (kt) + s * 32);   \
      B_[s][0] = *(const bf16x8*)(b0p + (kt) + s * 32);   \
      B_[s][1] = *(const bf16x8*)(b1p + (kt) + s * 32);   \
    }                                                     \
  }
  K4_LD(ca, cb, 0)
  for (int kt = 0; kt < Ssz; kt += 64) {
    if (kt + 64 < Ssz) K4_LD(na, nb, kt + 64)
#pragma unroll
    for (int s = 0; s < 2; ++s)
#pragma unroll
      for (int t = 0; t < 2; ++t)
#pragma unroll
        for (int u = 0; u < 2; ++u) acc[t][u] = MFMA(ca[s][t], cb[s][u], acc[t][u]);
    if (kt + 64 < Ssz) {
#pragma unroll
      for (int s = 0; s < 2; ++s)
#pragma unroll
        for (int t = 0; t < 2; ++t) { ca[s][t] = na[s][t]; cb[s][t] = nb[s][t]; }
    }
  }
#undef K4_LD
#pragma unroll
  for (int t = 0; t < 2; ++t)
#pragma unroll
    for (int r = 0; r < 4; ++r) {
      int row = i0 + wr * 32 + t * 16 + q4 + r;
      f32x4 sv = *(const f32x4*)&sums[((((b << 10) + row) << 4) + h) * 4];
      float inv = 1.f / (sv[0] + sv[1] + sv[2] + sv[3]);
#pragma unroll
      for (int u = 0; u < 2; ++u) {
        int d = wc * 32 + u * 16 + l15;
        aout[(size_t)(b * Ssz + row) * Dsz + h * DHsz + d] = (bf16)(acc[t][u][r] * inv);
      }
    }
}

// ---------------------------------------------------------------------------
// K5: out = aout_bf @ ow_h^T. LDS-FREE, register double-buffer, fp32 out.
// ---------------------------------------------------------------------------
__global__ __launch_bounds__(256, 4) void k5_out(const bf16* __restrict__ A,
                                                 const bf16* __restrict__ B,
                                                 float* __restrict__ C) {
  const int tid = threadIdx.x;
  const int lane = tid & 63, wv = tid >> 6;
  const int wr = wv >> 1, wc = wv & 1;
  const int l15 = lane & 15, q8 = (lane >> 4) << 3, q4 = (lane >> 4) << 2;
  const int m0 = blockIdx.y * 64, n0 = blockIdx.x * 64;
  const bf16* a0p = A + (size_t)(m0 + wr * 32 + l15) * Dsz + q8;
  const bf16* a1p = a0p + 16 * Dsz;
  const bf16* b0p = B + (size_t)(n0 + wc * 32 + l15) * Dsz + q8;
  const bf16* b1p = b0p + 16 * Dsz;

  f32x4 acc[2][2];
#pragma unroll
  for (int t = 0; t < 2; ++t)
#pragma unroll
    for (int u = 0; u < 2; ++u)
#pragma unroll
      for (int r = 0; r < 4; ++r) acc[t][u][r] = 0.f;

  bf16x8 ca[2][2], cb[2][2], na[2][2], nb[2][2];
#define K5_LD(A_, B_, kt)                                 \
  {                                                       \
    _Pragma("unroll") for (int s = 0; s < 2; ++s) {       \
      A_[s][0] = *(const bf16x8*)(a0p + (kt) + s * 32);   \
      A_[s][1] = *(const bf16x8*)(a1p + (kt) + s * 32);   \
      B_[s][0] = *(const bf16x8*)(b0p + (kt) + s * 32);   \
      B_[s][1] = *(const bf16x8*)(b1p + (kt) + s * 32);   \
    }                                                     \
  }
  K5_LD(ca, cb, 0)
  for (int kt = 0; kt < Dsz; kt += 64) {
    if (kt + 64 < Dsz) K5_LD(na, nb, kt + 64)
#pragma unroll
    for (int s = 0; s < 2; ++s)
#pragma unroll
      for (int t = 0; t < 2; ++t)
#pragma unroll
        for (int u = 0; u < 2; ++u) acc[t][u] = MFMA(ca[s][t], cb[s][u], acc[t][u]);
    if (kt + 64 < Dsz) {
#pragma unroll
      for (int s = 0; s < 2; ++s)
#pragma unroll
        for (int t = 0; t < 2; ++t) { ca[s][t] = na[s][t]; cb[s][t] = nb[s][t]; }
    }
  }
#undef K5_LD
#pragma unroll
  for (int t = 0; t < 2; ++t)
#pragma unroll
    for (int u = 0; u < 2; ++u) {
      int col = n0 + wc * 32 + u * 16 + l15;
#pragma unroll
      for (int r = 0; r < 4; ++r) {
        int row = m0 + wr * 32 + t * 16 + q4 + r;
        C[(size_t)row * Dsz + col] = acc[t][u][r];
      }
    }
}

// ---------------------------------------------------------------------------
extern "C" void kernel_launch(void* const* d_in, const int* in_sizes, int n_in,
                              void* d_out, int out_size, void* d_ws, size_t ws_size,
                              hipStream_t stream) {
  const float* x      = (const float*)d_in[0];
  const float* qkv_w  = (const float*)d_in[1];
  const float* out_w  = (const float*)d_in[2];
  const float* bias_p = (const float*)d_in[3];
  const float* bias_a = (const float*)d_in[4];
  const float* w1     = (const float*)d_in[5];
  const float* b1     = (const float*)d_in[6];
  const float* w2     = (const float*)d_in[7];
  const float* b2     = (const float*)d_in[8];
  float* out = (float*)d_out;

  // ws layout (bytes). scores (64 MB) ALIASES x_h/w_h (dead after k1).
  char* ws = (char*)d_ws;
  const size_t MB = 1ull << 20;
  bf16* ow_h   = (bf16*)(ws + 0 * MB);            // 2 MB
  bf16* qkv_bf = (bf16*)(ws + 2 * MB);            // 12 MB
  bf16* v_t    = (bf16*)(ws + 14 * MB);           // 4 MB
  bf16* aout   = (bf16*)(ws + 18 * MB);           // 4 MB
  float* sums  = (float*)(ws + 22 * MB);          // 512 KB [b][i][h][chunk]
  bf16* wf     = (bf16*)(ws + 22 * MB + 524288);  // 2 KB
  float2* tk   = (float2*)(ws + 22 * MB + 589824);// 256 KB [o][n]
  bf16* x_h    = (bf16*)(ws + 23 * MB);           // 4 MB   (dead after k1)
  bf16* w_h    = (bf16*)(ws + 27 * MB);           // 6 MB   (dead after k1)
  bf16* sc_bf  = (bf16*)(ws + 23 * MB);           // 64 MB, ends at 87 MB

  cast3<<<6144, 256, 0, stream>>>(x, qkv_w, out_w, x_h, w_h, ow_h);
  tkw<<<129, 256, 0, stream>>>(bias_p, bias_a, w1, b1, w2, tk, wf);

  k1_qkv<<<dim3(QKV3 / 96, (Bsz * Ssz) / 128), 256, 0, stream>>>(x_h, w_h, qkv_bf);
  pack_vt<<<dim3(Ssz / 64, Bsz * Hn), 256, 0, stream>>>(qkv_bf, v_t);

  k2_qk<<<dim3(Ssz / 128, Ssz / 128, Bsz * Hn), 256, 0, stream>>>(qkv_bf, sc_bf);
  dape_softmax<<<dim3(4, Ssz, Bsz), 256, 0, stream>>>(sc_bf, tk, wf, b2, sums);
  k4_av<<<dim3(Ssz / 64, Hn, Bsz), 256, 0, stream>>>(sc_bf, v_t, sums, aout);

  k5_out<<<dim3(Dsz / 64, (Bsz * Ssz) / 64), 256, 0, stream>>>(aout, ow_h, out);
}